// Round 12
// baseline (237.119 us; speedup 1.0000x reference)
//
#include <hip/hip_runtime.h>
#include <hip/hip_fp16.h>
#include <type_traits>

// ---------------------------------------------------------------------------
// GCN 3-layer forward: N=50000, E=600000, dims 128 -> 128 -> 64 -> 16.
// CSR (packed int2 {src, w}) built once per call, reused by all layers.
// 7-kernel pipeline:
//   gemm1 (CSR-independent, launched first) | count -> alloc -> scatter
//   aggmm2: t2 = relu(Agg(t1)+b1) @ W2      (fused gather+MFMA)
//   aggmm3: t3 = relu(Agg(t2)+b2) @ W3      (fused gather+MFMA)
//   agg3:   out = Agg(t3) + b3              (f32 out)
// All tables fp16. Gather MLP comes from PAIR-INTERLEAVING two nodes per
// lane-group (2 x EU=4 = 8 independent 16B loads in flight in the joint
// portion) -- round-11's EU=8 single-node unroll regressed because mean
// degree is only 12 and the tail ran 1-at-a-time.
// MFMA layouts (guide-verified): A[m=lane&15][k=quad*8+j], B mirror,
// C/D col=lane&15 row=quad*4+reg.
// ---------------------------------------------------------------------------

typedef _Float16 f16x8 __attribute__((ext_vector_type(8)));
typedef float f32x4 __attribute__((ext_vector_type(4)));

__device__ inline float2 h2f(unsigned int u) {
  __half2 h = __builtin_bit_cast(__half2, u);
  return __half22float2(h);
}

// acc0/acc1 += w * fp16x8(g)
__device__ inline void fma8h(float4& a0, float4& a1, const uint4& g, float w) {
  float2 f0 = h2f(g.x), f1 = h2f(g.y), f2 = h2f(g.z), f3 = h2f(g.w);
  a0.x = fmaf(f0.x, w, a0.x);
  a0.y = fmaf(f0.y, w, a0.y);
  a0.z = fmaf(f1.x, w, a0.z);
  a0.w = fmaf(f1.y, w, a0.w);
  a1.x = fmaf(f2.x, w, a1.x);
  a1.y = fmaf(f2.y, w, a1.y);
  a1.z = fmaf(f3.x, w, a1.z);
  a1.w = fmaf(f3.y, w, a1.w);
}

__device__ inline unsigned int pack2h(float x, float y) {
  __half2 h = __floats2half2_rn(x, y);
  return __builtin_bit_cast(unsigned int, h);
}

__device__ inline uint2 pack4h(const float4& v) {
  uint2 r;
  r.x = pack2h(v.x, v.y);
  r.y = pack2h(v.z, v.w);
  return r;
}

// ------------------------------- CSR build ---------------------------------

__global__ void count_kernel(const int* __restrict__ dst, int* __restrict__ cnt, int E) {
  int e = blockIdx.x * blockDim.x + threadIdx.x;
  if (e < E) atomicAdd(&cnt[dst[e]], 1);
}

__global__ void alloc_kernel(const int* __restrict__ cnt, int* __restrict__ row_start,
                             int* __restrict__ cursor, int* __restrict__ counter,
                             float* __restrict__ dinv, int n) {
  __shared__ int sbuf[256];
  __shared__ int sbase;
  int t = threadIdx.x;
  int node = blockIdx.x * 256 + t;
  int c = (node < n) ? cnt[node] : 0;
  if (node < n) dinv[node] = rsqrtf((float)c + 1.0f);
  sbuf[t] = c;
  __syncthreads();
#pragma unroll
  for (int offs = 1; offs < 256; offs <<= 1) {
    int v = sbuf[t];
    int add = (t >= offs) ? sbuf[t - offs] : 0;
    __syncthreads();
    sbuf[t] = v + add;
    __syncthreads();
  }
  if (t == 255) sbase = atomicAdd(counter, sbuf[255]);
  __syncthreads();
  if (node < n) {
    int excl = sbuf[t] - c;
    row_start[node] = sbase + excl;
    cursor[node] = sbase + excl;
  }
}

__global__ void scatter_kernel(const int* __restrict__ src, const int* __restrict__ dst,
                               const float* __restrict__ dinv, int* __restrict__ cursor,
                               int2* __restrict__ csr, int E) {
  int e = blockIdx.x * blockDim.x + threadIdx.x;
  if (e < E) {
    int s = src[e];
    int d = dst[e];
    int pos = atomicAdd(&cursor[d], 1);
    int2 pk;
    pk.x = s;
    pk.y = __float_as_int(dinv[s] * dinv[d]);
    csr[pos] = pk;
  }
}

// ------------------------- Gather helpers ----------------------------------
// Single-node gather, EU-edge unroll. Lane covers chunk fl (uint4 = 8 halves).
template <int K, int EU>
__device__ inline void gather_node(const uint4* __restrict__ h4, int nd, float sc,
                                   const int* __restrict__ row_start,
                                   const int* __restrict__ cnt,
                                   const int2* __restrict__ csr, int fl,
                                   float4 (&acc)[2]) {
  constexpr int RS = K / 8;
  {
    uint4 sv = h4[(size_t)nd * RS + fl];
    fma8h(acc[0], acc[1], sv, sc);
  }
  int j = row_start[nd];
  int e = j + cnt[nd];
  for (; j + EU <= e; j += EU) {
    int2 p[EU];
    uint4 g[EU];
#pragma unroll
    for (int u = 0; u < EU; ++u) p[u] = csr[j + u];
#pragma unroll
    for (int u = 0; u < EU; ++u) g[u] = h4[(size_t)p[u].x * RS + fl];
#pragma unroll
    for (int u = 0; u < EU; ++u) fma8h(acc[0], acc[1], g[u], __int_as_float(p[u].y));
  }
  for (; j < e; ++j) {
    int2 p = csr[j];
    uint4 g = h4[(size_t)p.x * RS + fl];
    fma8h(acc[0], acc[1], g, __int_as_float(p.y));
  }
}

// Pair gather: two nodes interleaved; joint loop issues 2*EU independent
// loads per step; remainders fall back to EU blocks + singles.
template <int K, int EU>
__device__ inline void gather_pair(const uint4* __restrict__ h4, int nd0, int nd1,
                                   float sc0, float sc1,
                                   const int* __restrict__ row_start,
                                   const int* __restrict__ cnt,
                                   const int2* __restrict__ csr, int fl,
                                   float4 (&a0)[2], float4 (&a1)[2]) {
  constexpr int RS = K / 8;
  {
    uint4 sv0 = h4[(size_t)nd0 * RS + fl];
    uint4 sv1 = h4[(size_t)nd1 * RS + fl];
    fma8h(a0[0], a0[1], sv0, sc0);
    fma8h(a1[0], a1[1], sv1, sc1);
  }
  int j0 = row_start[nd0], c0 = cnt[nd0];
  int j1 = row_start[nd1], c1 = cnt[nd1];
  int e0 = j0 + c0, e1 = j1 + c1;
  int joint = (c0 < c1 ? c0 : c1) / EU;
  for (int it = 0; it < joint; ++it) {
    int2 p0[EU], p1[EU];
#pragma unroll
    for (int u = 0; u < EU; ++u) {
      p0[u] = csr[j0 + u];
      p1[u] = csr[j1 + u];
    }
    uint4 g0[EU], g1[EU];
#pragma unroll
    for (int u = 0; u < EU; ++u) {
      g0[u] = h4[(size_t)p0[u].x * RS + fl];
      g1[u] = h4[(size_t)p1[u].x * RS + fl];
    }
#pragma unroll
    for (int u = 0; u < EU; ++u) {
      fma8h(a0[0], a0[1], g0[u], __int_as_float(p0[u].y));
      fma8h(a1[0], a1[1], g1[u], __int_as_float(p1[u].y));
    }
    j0 += EU;
    j1 += EU;
  }
  // node0 remainder
  for (; j0 + EU <= e0; j0 += EU) {
    int2 p[EU];
    uint4 g[EU];
#pragma unroll
    for (int u = 0; u < EU; ++u) p[u] = csr[j0 + u];
#pragma unroll
    for (int u = 0; u < EU; ++u) g[u] = h4[(size_t)p[u].x * RS + fl];
#pragma unroll
    for (int u = 0; u < EU; ++u) fma8h(a0[0], a0[1], g[u], __int_as_float(p[u].y));
  }
  for (; j0 < e0; ++j0) {
    int2 p = csr[j0];
    uint4 g = h4[(size_t)p.x * RS + fl];
    fma8h(a0[0], a0[1], g, __int_as_float(p.y));
  }
  // node1 remainder
  for (; j1 + EU <= e1; j1 += EU) {
    int2 p[EU];
    uint4 g[EU];
#pragma unroll
    for (int u = 0; u < EU; ++u) p[u] = csr[j1 + u];
#pragma unroll
    for (int u = 0; u < EU; ++u) g[u] = h4[(size_t)p[u].x * RS + fl];
#pragma unroll
    for (int u = 0; u < EU; ++u) fma8h(a1[0], a1[1], g[u], __int_as_float(p[u].y));
  }
  for (; j1 < e1; ++j1) {
    int2 p = csr[j1];
    uint4 g = h4[(size_t)p.x * RS + fl];
    fma8h(a1[0], a1[1], g, __int_as_float(p.y));
  }
}

// --------------------------------- GEMM (MFMA) -----------------------------
// C16[n x F] = A[n x K] @ W[K x F]; W (f32) transposed+converted to fp16 LDS
// Ws[F][K+8] during staging. 4 waves x 16 rows per block.
template <int K, int F, typename TIN>
__global__ __launch_bounds__(256) void gemm_mfma(const TIN* __restrict__ A,
                                                 const float* __restrict__ W,
                                                 __half* __restrict__ C16, int n,
                                                 int nwaves) {
  constexpr int KP = K + 8;
  constexpr int KS = K / 32;
  constexpr int NT = F / 16;

  __shared__ __half Ws[F * KP];

  int t = threadIdx.x;
  for (int i = t; i < K * F; i += 256) {
    int kk = i / F, nn = i % F;
    Ws[nn * KP + kk] = __float2half(W[i]);
  }
  __syncthreads();  // only barrier

  int wave = blockIdx.x * 4 + (t >> 6);
  if (wave >= nwaves) return;
  int lane = t & 63;
  int m = lane & 15;
  int quad = lane >> 4;

  int arow = wave * 16 + m;
  if (arow >= n) arow = n - 1;  // clamp loads; stores guarded

  f16x8 af[KS];
  if constexpr (std::is_same_v<TIN, float>) {
#pragma unroll
    for (int ks = 0; ks < KS; ++ks) {
      const float* p = A + (size_t)arow * K + ks * 32 + quad * 8;
      float4 lo = *(const float4*)p;
      float4 hi = *(const float4*)(p + 4);
      f16x8 a;
      a[0] = (_Float16)lo.x; a[1] = (_Float16)lo.y;
      a[2] = (_Float16)lo.z; a[3] = (_Float16)lo.w;
      a[4] = (_Float16)hi.x; a[5] = (_Float16)hi.y;
      a[6] = (_Float16)hi.z; a[7] = (_Float16)hi.w;
      af[ks] = a;
    }
  } else {
#pragma unroll
    for (int ks = 0; ks < KS; ++ks)
      af[ks] = *(const f16x8*)(const void*)&A[(size_t)arow * K + ks * 32 + quad * 8];
  }

  f32x4 acc[NT];
#pragma unroll
  for (int nt = 0; nt < NT; ++nt) acc[nt] = (f32x4){0.f, 0.f, 0.f, 0.f};
#pragma unroll
  for (int nt = 0; nt < NT; ++nt)
#pragma unroll
    for (int ks = 0; ks < KS; ++ks) {
      f16x8 b = *(const f16x8*)(const void*)&Ws[(nt * 16 + m) * KP + ks * 32 + quad * 8];
      acc[nt] = __builtin_amdgcn_mfma_f32_16x16x32_f16(af[ks], b, acc[nt], 0, 0, 0);
    }

  int rbase = wave * 16 + quad * 4;
#pragma unroll
  for (int nt = 0; nt < NT; ++nt)
#pragma unroll
    for (int r = 0; r < 4; ++r) {
      int rr = rbase + r;
      if (rr < n) C16[(size_t)rr * F + nt * 16 + m] = __float2half(acc[nt][r]);
    }
}

// ---------------------- Fused aggregate + GEMM (MFMA) ----------------------
// C16[n x F] = relu(Agg(hprev) + bias) @ W,  hprev [n][K] fp16, W [K][F] f32.
// Per wave: 16 nodes; TPN=K/8 lanes/node; node-batches processed in PAIRS
// (interleaved gather -> 8 loads in flight). Agg result packed to
// wave-private LDS As[16][K+8] fp16, then MFMA (no inter-phase barrier).
template <int K, int F>
__global__ __launch_bounds__(256) void aggmm(
    const __half* __restrict__ hprev, const float* __restrict__ W,
    const float* __restrict__ bias, const int* __restrict__ row_start,
    const int* __restrict__ cnt, const int2* __restrict__ csr,
    const float* __restrict__ dinv, __half* __restrict__ C16, int n, int nwaves) {
  constexpr int KP = K + 8;
  constexpr int KS = K / 32;
  constexpr int NT = F / 16;
  constexpr int TPN = K / 8;       // lanes per node (16B chunk each)
  constexpr int NPB = 64 / TPN;    // nodes per batch (128->4, 64->8)
  constexpr int NBATCH = 16 / NPB; // batches (4, 2) -- even, processed in pairs

  __shared__ __half Ws[F * KP];
  __shared__ __half AsS[4][16 * KP];

  int t = threadIdx.x;
  for (int i = t; i < K * F; i += 256) {
    int kk = i / F, nn = i % F;
    Ws[nn * KP + kk] = __float2half(W[i]);
  }
  __syncthreads();  // only barrier

  int wid = t >> 6;
  int wave = blockIdx.x * 4 + wid;
  if (wave >= nwaves) return;
  int lane = t & 63;
  __half* As = AsS[wid];

  // ---- aggregation phase (paired) ----
  int sub = lane / TPN;
  int fl = lane % TPN;
  const uint4* h4 = (const uint4*)hprev;
  float4 b0 = *(const float4*)&bias[fl * 8];
  float4 b1 = *(const float4*)&bias[fl * 8 + 4];
#pragma unroll
  for (int pb = 0; pb < NBATCH / 2; ++pb) {
    int node0 = wave * 16 + (pb * 2 + 0) * NPB + sub;
    int node1 = wave * 16 + (pb * 2 + 1) * NPB + sub;
    int nd0 = node0 < n ? node0 : n - 1;  // clamp (dup rows OK; C-store guarded)
    int nd1 = node1 < n ? node1 : n - 1;
    float di0 = dinv[nd0];
    float di1 = dinv[nd1];
    float4 a0[2] = {make_float4(0.f, 0.f, 0.f, 0.f), make_float4(0.f, 0.f, 0.f, 0.f)};
    float4 a1[2] = {make_float4(0.f, 0.f, 0.f, 0.f), make_float4(0.f, 0.f, 0.f, 0.f)};
    gather_pair<K, 4>(h4, nd0, nd1, di0 * di0, di1 * di1, row_start, cnt, csr, fl, a0, a1);
#pragma unroll
    for (int half = 0; half < 2; ++half) {
      float4 (&aa)[2] = half ? a1 : a0;
      float4 r0 = make_float4(fmaxf(aa[0].x + b0.x, 0.f), fmaxf(aa[0].y + b0.y, 0.f),
                              fmaxf(aa[0].z + b0.z, 0.f), fmaxf(aa[0].w + b0.w, 0.f));
      float4 r1 = make_float4(fmaxf(aa[1].x + b1.x, 0.f), fmaxf(aa[1].y + b1.y, 0.f),
                              fmaxf(aa[1].z + b1.z, 0.f), fmaxf(aa[1].w + b1.w, 0.f));
      uint2 lo = pack4h(r0), hi = pack4h(r1);
      uint4 pk;
      pk.x = lo.x; pk.y = lo.y; pk.z = hi.x; pk.w = hi.y;
      *(uint4*)&As[((pb * 2 + half) * NPB + sub) * KP + fl * 8] = pk;
    }
  }

  // ---- MFMA phase ----
  int m = lane & 15;
  int quad = lane >> 4;
  f16x8 af[KS];
#pragma unroll
  for (int ks = 0; ks < KS; ++ks)
    af[ks] = *(const f16x8*)(const void*)&As[m * KP + ks * 32 + quad * 8];

  f32x4 acc2[NT];
#pragma unroll
  for (int nt = 0; nt < NT; ++nt) acc2[nt] = (f32x4){0.f, 0.f, 0.f, 0.f};
#pragma unroll
  for (int nt = 0; nt < NT; ++nt)
#pragma unroll
    for (int ks = 0; ks < KS; ++ks) {
      f16x8 bfr = *(const f16x8*)(const void*)&Ws[(nt * 16 + m) * KP + ks * 32 + quad * 8];
      acc2[nt] = __builtin_amdgcn_mfma_f32_16x16x32_f16(af[ks], bfr, acc2[nt], 0, 0, 0);
    }

  int rbase = wave * 16 + quad * 4;
#pragma unroll
  for (int nt = 0; nt < NT; ++nt)
#pragma unroll
    for (int r = 0; r < 4; ++r) {
      int rr = rbase + r;
      if (rr < n) C16[(size_t)rr * F + nt * 16 + m] = __float2half(acc2[nt][r]);
    }
}

// ------------------------------ Final aggregation --------------------------
// out[i] = Agg(h16)[i] + bias   (f32 out, F=16, TPN=2, EU=4)
__global__ __launch_bounds__(256) void agg_final(
    const __half* __restrict__ h16, const int* __restrict__ row_start,
    const int* __restrict__ cnt, const int2* __restrict__ csr,
    const float* __restrict__ dinv, const float* __restrict__ bias,
    float* __restrict__ out, int n) {
  constexpr int F = 16;
  constexpr int TPN = 2;
  constexpr int NPB = 256 / TPN;
  int node = blockIdx.x * NPB + threadIdx.x / TPN;
  int lane = threadIdx.x % TPN;
  if (node >= n) return;

  const uint4* h4 = (const uint4*)h16;
  float di = dinv[node];
  float4 acc[2] = {make_float4(0.f, 0.f, 0.f, 0.f), make_float4(0.f, 0.f, 0.f, 0.f)};
  gather_node<F, 4>(h4, node, di * di, row_start, cnt, csr, lane, acc);

  float4 b0 = *(const float4*)&bias[lane * 8];
  float4 b1 = *(const float4*)&bias[lane * 8 + 4];
  float4 r0 = make_float4(acc[0].x + b0.x, acc[0].y + b0.y, acc[0].z + b0.z, acc[0].w + b0.w);
  float4 r1 = make_float4(acc[1].x + b1.x, acc[1].y + b1.y, acc[1].z + b1.z, acc[1].w + b1.w);
  float* op = &out[(size_t)node * F + lane * 8];
  *(float4*)op = r0;
  *(float4*)(op + 4) = r1;
}

// -------------------------------- launch -----------------------------------

extern "C" void kernel_launch(void* const* d_in, const int* in_sizes, int n_in,
                              void* d_out, int out_size, void* d_ws, size_t ws_size,
                              hipStream_t stream) {
  const float* x = (const float*)d_in[0];
  const int* edge = (const int*)d_in[1];
  const float* W1 = (const float*)d_in[2];
  const float* b1 = (const float*)d_in[3];
  const float* W2 = (const float*)d_in[4];
  const float* b2 = (const float*)d_in[5];
  const float* W3 = (const float*)d_in[6];
  const float* b3 = (const float*)d_in[7];

  const int N = in_sizes[0] / 128;
  const int E = in_sizes[1] / 2;
  const int* src = edge;       // edge_index[0]
  const int* dstp = edge + E;  // edge_index[1]
  float* out = (float*)d_out;

  size_t off = 0;
  auto take = [&](size_t bytes) -> void* {
    void* r = (char*)d_ws + off;
    off += (bytes + 255) & ~(size_t)255;
    return r;
  };
  int* counter = (int*)take(4);
  int* cnt = (int*)take((size_t)N * 4);
  float* dinv = (float*)take((size_t)N * 4);
  int* row_start = (int*)take((size_t)N * 4);
  int* cursor = (int*)take((size_t)N * 4);
  int2* csr = (int2*)take((size_t)E * 8);
  __half* t1 = (__half*)take((size_t)N * 128 * 2);  // gemm1 out
  __half* t2 = (__half*)take((size_t)N * 64 * 2);   // aggmm2 out
  __half* t3 = (__half*)take((size_t)N * 16 * 2);   // aggmm3 out

  // zero counter + cnt (first two regions, contiguous)
  hipMemsetAsync(d_ws, 0, 256 + (size_t)N * 4, stream);

  const int TB = 256;
  int eg = (E + TB - 1) / TB;
  int ng = (N + TB - 1) / TB;
  int nwaves = (N + 15) / 16;   // 16 rows per wave -> 3125
  int gblk = (nwaves + 3) / 4;  // 4 waves per 256-thr block -> 782

  // gemm1 is CSR-independent; CSR build follows it in the queue.
  gemm_mfma<128, 128, float><<<gblk, 256, 0, stream>>>(x, W1, t1, N, nwaves);
  count_kernel<<<eg, TB, 0, stream>>>(dstp, cnt, E);
  alloc_kernel<<<ng, TB, 0, stream>>>(cnt, row_start, cursor, counter, dinv, N);
  scatter_kernel<<<eg, TB, 0, stream>>>(src, dstp, dinv, cursor, csr, E);

  // t2 = relu(Agg(t1)+b1) @ W2
  aggmm<128, 64><<<gblk, 256, 0, stream>>>(t1, W2, b1, row_start, cnt, csr, dinv, t2, N,
                                           nwaves);
  // t3 = relu(Agg(t2)+b2) @ W3
  aggmm<64, 16><<<gblk, 256, 0, stream>>>(t2, W3, b2, row_start, cnt, csr, dinv, t3, N,
                                          nwaves);
  // out = Agg(t3) + b3
  agg_final<<<(N + 127) / 128, 256, 0, stream>>>(t3, row_start, cnt, csr, dinv, b3, out, N);
}

// Round 13
// 208.814 us; speedup vs baseline: 1.1356x; 1.1356x over previous
//
#include <hip/hip_runtime.h>
#include <hip/hip_fp16.h>
#include <type_traits>

// ---------------------------------------------------------------------------
// GCN 3-layer forward: N=50000, E=600000, dims 128 -> 128 -> 64 -> 16.
// CSR (packed int2 {src, w}) built once per call, reused by all layers.
// Pipeline: gemm1 | count -> alloc -> scatter ; aggmm2 ; aggmm3 ; agg_final.
// All inter-layer tables fp16.
// aggmm (fused Agg+GEMM) round-13 restructure: 512-thr blocks, ALL 8 waves
// gather (8 nodes/wave, TPN=8, EU=4 -> up to 8 loads in flight/lane) into
// shared As[64][K+8]; one barrier; waves 0-3 run the 4 MFMA tiles. This
// doubles gather-phase wave count (r10-12 tied waves to N/16 -> 18% occupancy,
// latency-bound at 50us with VALU 17% / HBM 18% -- the counters' verdict).
// agg_final: edge-list split across 2 lane-groups/node + shfl combine (2x waves).
// MFMA layouts (guide-verified): A[m=lane&15][k=quad*8+j], B mirror,
// C/D col=lane&15 row=quad*4+reg.
// ---------------------------------------------------------------------------

typedef _Float16 f16x8 __attribute__((ext_vector_type(8)));
typedef float f32x4 __attribute__((ext_vector_type(4)));

__device__ inline float2 h2f(unsigned int u) {
  __half2 h = __builtin_bit_cast(__half2, u);
  return __half22float2(h);
}

// acc0/acc1 += w * fp16x8(g)
__device__ inline void fma8h(float4& a0, float4& a1, const uint4& g, float w) {
  float2 f0 = h2f(g.x), f1 = h2f(g.y), f2 = h2f(g.z), f3 = h2f(g.w);
  a0.x = fmaf(f0.x, w, a0.x);
  a0.y = fmaf(f0.y, w, a0.y);
  a0.z = fmaf(f1.x, w, a0.z);
  a0.w = fmaf(f1.y, w, a0.w);
  a1.x = fmaf(f2.x, w, a1.x);
  a1.y = fmaf(f2.y, w, a1.y);
  a1.z = fmaf(f3.x, w, a1.z);
  a1.w = fmaf(f3.y, w, a1.w);
}

__device__ inline unsigned int pack2h(float x, float y) {
  __half2 h = __floats2half2_rn(x, y);
  return __builtin_bit_cast(unsigned int, h);
}

__device__ inline uint2 pack4h(const float4& v) {
  uint2 r;
  r.x = pack2h(v.x, v.y);
  r.y = pack2h(v.z, v.w);
  return r;
}

// ------------------------------- CSR build ---------------------------------

__global__ void count_kernel(const int* __restrict__ dst, int* __restrict__ cnt, int E) {
  int e = blockIdx.x * blockDim.x + threadIdx.x;
  if (e < E) atomicAdd(&cnt[dst[e]], 1);
}

__global__ void alloc_kernel(const int* __restrict__ cnt, int* __restrict__ row_start,
                             int* __restrict__ cursor, int* __restrict__ counter,
                             float* __restrict__ dinv, int n) {
  __shared__ int sbuf[256];
  __shared__ int sbase;
  int t = threadIdx.x;
  int node = blockIdx.x * 256 + t;
  int c = (node < n) ? cnt[node] : 0;
  if (node < n) dinv[node] = rsqrtf((float)c + 1.0f);
  sbuf[t] = c;
  __syncthreads();
#pragma unroll
  for (int offs = 1; offs < 256; offs <<= 1) {
    int v = sbuf[t];
    int add = (t >= offs) ? sbuf[t - offs] : 0;
    __syncthreads();
    sbuf[t] = v + add;
    __syncthreads();
  }
  if (t == 255) sbase = atomicAdd(counter, sbuf[255]);
  __syncthreads();
  if (node < n) {
    int excl = sbuf[t] - c;
    row_start[node] = sbase + excl;
    cursor[node] = sbase + excl;
  }
}

__global__ void scatter_kernel(const int* __restrict__ src, const int* __restrict__ dst,
                               const float* __restrict__ dinv, int* __restrict__ cursor,
                               int2* __restrict__ csr, int E) {
  int e = blockIdx.x * blockDim.x + threadIdx.x;
  if (e < E) {
    int s = src[e];
    int d = dst[e];
    int pos = atomicAdd(&cursor[d], 1);
    int2 pk;
    pk.x = s;
    pk.y = __float_as_int(dinv[s] * dinv[d]);
    csr[pos] = pk;
  }
}

// --------------------------------- GEMM (MFMA) -----------------------------
// C16[n x F] = A[n x K] @ W[K x F]; W (f32) transposed+converted to fp16 LDS
// Ws[F][K+8] during staging. 4 waves x 16 rows per block.
template <int K, int F, typename TIN>
__global__ __launch_bounds__(256) void gemm_mfma(const TIN* __restrict__ A,
                                                 const float* __restrict__ W,
                                                 __half* __restrict__ C16, int n,
                                                 int nwaves) {
  constexpr int KP = K + 8;
  constexpr int KS = K / 32;
  constexpr int NT = F / 16;

  __shared__ __half Ws[F * KP];

  int t = threadIdx.x;
  for (int i = t; i < K * F; i += 256) {
    int kk = i / F, nn = i % F;
    Ws[nn * KP + kk] = __float2half(W[i]);
  }
  __syncthreads();  // only barrier

  int wave = blockIdx.x * 4 + (t >> 6);
  if (wave >= nwaves) return;
  int lane = t & 63;
  int m = lane & 15;
  int quad = lane >> 4;

  int arow = wave * 16 + m;
  if (arow >= n) arow = n - 1;  // clamp loads; stores guarded

  f16x8 af[KS];
  if constexpr (std::is_same_v<TIN, float>) {
#pragma unroll
    for (int ks = 0; ks < KS; ++ks) {
      const float* p = A + (size_t)arow * K + ks * 32 + quad * 8;
      float4 lo = *(const float4*)p;
      float4 hi = *(const float4*)(p + 4);
      f16x8 a;
      a[0] = (_Float16)lo.x; a[1] = (_Float16)lo.y;
      a[2] = (_Float16)lo.z; a[3] = (_Float16)lo.w;
      a[4] = (_Float16)hi.x; a[5] = (_Float16)hi.y;
      a[6] = (_Float16)hi.z; a[7] = (_Float16)hi.w;
      af[ks] = a;
    }
  } else {
#pragma unroll
    for (int ks = 0; ks < KS; ++ks)
      af[ks] = *(const f16x8*)(const void*)&A[(size_t)arow * K + ks * 32 + quad * 8];
  }

  f32x4 acc[NT];
#pragma unroll
  for (int nt = 0; nt < NT; ++nt) acc[nt] = (f32x4){0.f, 0.f, 0.f, 0.f};
#pragma unroll
  for (int nt = 0; nt < NT; ++nt)
#pragma unroll
    for (int ks = 0; ks < KS; ++ks) {
      f16x8 b = *(const f16x8*)(const void*)&Ws[(nt * 16 + m) * KP + ks * 32 + quad * 8];
      acc[nt] = __builtin_amdgcn_mfma_f32_16x16x32_f16(af[ks], b, acc[nt], 0, 0, 0);
    }

  int rbase = wave * 16 + quad * 4;
#pragma unroll
  for (int nt = 0; nt < NT; ++nt)
#pragma unroll
    for (int r = 0; r < 4; ++r) {
      int rr = rbase + r;
      if (rr < n) C16[(size_t)rr * F + nt * 16 + m] = __float2half(acc[nt][r]);
    }
}

// ---------------------- Fused aggregate + GEMM (MFMA) ----------------------
// C16[n x F] = relu(Agg(hprev) + bias) @ W,  hprev [n][K] fp16, W [K][F] f32.
// Block = 512 thr (8 waves) = 64 nodes = 4 MFMA tiles.
// Gather: all 8 waves, 8 nodes each (TPN=8 lanes/node, CPL chunks/lane --
// chunk index fl + c*TPN keeps each 128B line covered by 8 lanes), EU=4 edge
// unroll -> EU*CPL loads in flight. Results -> As[64][K+8] fp16.
// One barrier. MFMA: waves 0-3, tile each.
template <int K, int F, int CPL, int EU>
__global__ __launch_bounds__(512) void aggmm(
    const __half* __restrict__ hprev, const float* __restrict__ W,
    const float* __restrict__ bias, const int* __restrict__ row_start,
    const int* __restrict__ cnt, const int2* __restrict__ csr,
    const float* __restrict__ dinv, __half* __restrict__ C16, int n) {
  constexpr int KP = K + 8;
  constexpr int KS = K / 32;
  constexpr int NT = F / 16;
  constexpr int TPN = 8;       // lanes per node
  constexpr int RS = K / 8;    // uint4 per row (TPN*CPL == RS)
  static_assert(TPN * CPL == RS, "chunk coverage");

  __shared__ __half Ws[F * KP];
  __shared__ __half As[64 * KP];

  int t = threadIdx.x;
  for (int i = t; i < K * F; i += 512) {
    int kk = i / F, nn = i % F;
    Ws[nn * KP + kk] = __float2half(W[i]);
  }

  int wid = t >> 6;
  int lane = t & 63;
  int nb = blockIdx.x * 64;

  // ---- gather phase (all 8 waves) ----
  {
    int sub = lane / TPN;  // node within wave (0..7)
    int fl = lane % TPN;   // chunk group
    int nib = wid * 8 + sub;  // node in block (0..63)
    int node = nb + nib;
    int nd = node < n ? node : n - 1;  // clamp (dup work OK; C-store guarded)
    const uint4* h4 = (const uint4*)hprev;
    float di = dinv[nd];
    float sc = di * di;
    float4 acc[CPL][2];
#pragma unroll
    for (int c = 0; c < CPL; ++c) {
      acc[c][0] = make_float4(0.f, 0.f, 0.f, 0.f);
      acc[c][1] = make_float4(0.f, 0.f, 0.f, 0.f);
    }
#pragma unroll
    for (int c = 0; c < CPL; ++c) {
      uint4 sv = h4[(size_t)nd * RS + fl + c * TPN];
      fma8h(acc[c][0], acc[c][1], sv, sc);
    }
    int j = row_start[nd];
    int e = j + cnt[nd];
    for (; j + EU <= e; j += EU) {
      int2 p[EU];
#pragma unroll
      for (int u = 0; u < EU; ++u) p[u] = csr[j + u];
      uint4 g[EU][CPL];
#pragma unroll
      for (int u = 0; u < EU; ++u)
#pragma unroll
        for (int c = 0; c < CPL; ++c) g[u][c] = h4[(size_t)p[u].x * RS + fl + c * TPN];
#pragma unroll
      for (int u = 0; u < EU; ++u)
#pragma unroll
        for (int c = 0; c < CPL; ++c)
          fma8h(acc[c][0], acc[c][1], g[u][c], __int_as_float(p[u].y));
    }
    for (; j < e; ++j) {
      int2 p = csr[j];
#pragma unroll
      for (int c = 0; c < CPL; ++c) {
        uint4 g = h4[(size_t)p.x * RS + fl + c * TPN];
        fma8h(acc[c][0], acc[c][1], g, __int_as_float(p.y));
      }
    }
#pragma unroll
    for (int c = 0; c < CPL; ++c) {
      int ch = fl + c * TPN;
      float4 b0 = *(const float4*)&bias[ch * 8];
      float4 b1 = *(const float4*)&bias[ch * 8 + 4];
      float4 r0 = make_float4(fmaxf(acc[c][0].x + b0.x, 0.f), fmaxf(acc[c][0].y + b0.y, 0.f),
                              fmaxf(acc[c][0].z + b0.z, 0.f), fmaxf(acc[c][0].w + b0.w, 0.f));
      float4 r1 = make_float4(fmaxf(acc[c][1].x + b1.x, 0.f), fmaxf(acc[c][1].y + b1.y, 0.f),
                              fmaxf(acc[c][1].z + b1.z, 0.f), fmaxf(acc[c][1].w + b1.w, 0.f));
      uint2 lo = pack4h(r0), hi = pack4h(r1);
      uint4 pk;
      pk.x = lo.x; pk.y = lo.y; pk.z = hi.x; pk.w = hi.y;
      *(uint4*)&As[(size_t)nib * KP + ch * 8] = pk;
    }
  }

  __syncthreads();

  // ---- MFMA phase (waves 0-3, one 16-row tile each) ----
  if (wid < 4) {
    int m = lane & 15;
    int quad = lane >> 4;
    const __half* At = &As[(size_t)wid * 16 * KP];
    f16x8 af[KS];
#pragma unroll
    for (int ks = 0; ks < KS; ++ks)
      af[ks] = *(const f16x8*)(const void*)&At[m * KP + ks * 32 + quad * 8];

    f32x4 acc2[NT];
#pragma unroll
    for (int nt = 0; nt < NT; ++nt) acc2[nt] = (f32x4){0.f, 0.f, 0.f, 0.f};
#pragma unroll
    for (int nt = 0; nt < NT; ++nt)
#pragma unroll
      for (int ks = 0; ks < KS; ++ks) {
        f16x8 bfr = *(const f16x8*)(const void*)&Ws[(nt * 16 + m) * KP + ks * 32 + quad * 8];
        acc2[nt] = __builtin_amdgcn_mfma_f32_16x16x32_f16(af[ks], bfr, acc2[nt], 0, 0, 0);
      }

    int rbase = nb + wid * 16 + quad * 4;
#pragma unroll
    for (int nt = 0; nt < NT; ++nt)
#pragma unroll
      for (int r = 0; r < 4; ++r) {
        int rr = rbase + r;
        if (rr < n) C16[(size_t)rr * F + nt * 16 + m] = __float2half(acc2[nt][r]);
      }
  }
}

// ------------------------------ Final aggregation --------------------------
// out[i] = Agg(h16)[i] + bias (f32 out, F=16). 4 lanes/node: 2 edge-halves x
// 2 chunk-lanes; halves combined via shfl_xor(2). 64 nodes/block.
__global__ __launch_bounds__(256) void agg_final(
    const __half* __restrict__ h16, const int* __restrict__ row_start,
    const int* __restrict__ cnt, const int2* __restrict__ csr,
    const float* __restrict__ dinv, const float* __restrict__ bias,
    float* __restrict__ out, int n) {
  int node = blockIdx.x * 64 + threadIdx.x / 4;
  int q = threadIdx.x & 3;
  int half = q >> 1;
  int fl = q & 1;
  bool valid = node < n;
  int nd = valid ? node : n - 1;

  const uint4* h4 = (const uint4*)h16;  // 2 uint4 per row
  float di = dinv[nd];
  float4 a0 = make_float4(0.f, 0.f, 0.f, 0.f);
  float4 a1 = make_float4(0.f, 0.f, 0.f, 0.f);
  if (half == 0) {
    uint4 sv = h4[(size_t)nd * 2 + fl];
    fma8h(a0, a1, sv, di * di);
  }
  int s = row_start[nd];
  int e = s + cnt[nd];
  int j = s + half;
  for (; j + 2 < e; j += 4) {  // edges j, j+2 (this half's stride-2 stream)
    int2 p0 = csr[j];
    int2 p1 = csr[j + 2];
    uint4 g0 = h4[(size_t)p0.x * 2 + fl];
    uint4 g1 = h4[(size_t)p1.x * 2 + fl];
    fma8h(a0, a1, g0, __int_as_float(p0.y));
    fma8h(a0, a1, g1, __int_as_float(p1.y));
  }
  for (; j < e; j += 2) {
    int2 p = csr[j];
    uint4 g = h4[(size_t)p.x * 2 + fl];
    fma8h(a0, a1, g, __int_as_float(p.y));
  }

  // combine the two edge-halves (xor lane by 2 keeps fl, flips half)
  a0.x += __shfl_xor(a0.x, 2);
  a0.y += __shfl_xor(a0.y, 2);
  a0.z += __shfl_xor(a0.z, 2);
  a0.w += __shfl_xor(a0.w, 2);
  a1.x += __shfl_xor(a1.x, 2);
  a1.y += __shfl_xor(a1.y, 2);
  a1.z += __shfl_xor(a1.z, 2);
  a1.w += __shfl_xor(a1.w, 2);

  if (valid && half == 0) {
    float4 b0 = *(const float4*)&bias[fl * 8];
    float4 b1 = *(const float4*)&bias[fl * 8 + 4];
    float4 r0 = make_float4(a0.x + b0.x, a0.y + b0.y, a0.z + b0.z, a0.w + b0.w);
    float4 r1 = make_float4(a1.x + b1.x, a1.y + b1.y, a1.z + b1.z, a1.w + b1.w);
    float* op = &out[(size_t)node * 16 + fl * 8];
    *(float4*)op = r0;
    *(float4*)(op + 4) = r1;
  }
}

// -------------------------------- launch -----------------------------------

extern "C" void kernel_launch(void* const* d_in, const int* in_sizes, int n_in,
                              void* d_out, int out_size, void* d_ws, size_t ws_size,
                              hipStream_t stream) {
  const float* x = (const float*)d_in[0];
  const int* edge = (const int*)d_in[1];
  const float* W1 = (const float*)d_in[2];
  const float* b1 = (const float*)d_in[3];
  const float* W2 = (const float*)d_in[4];
  const float* b2 = (const float*)d_in[5];
  const float* W3 = (const float*)d_in[6];
  const float* b3 = (const float*)d_in[7];

  const int N = in_sizes[0] / 128;
  const int E = in_sizes[1] / 2;
  const int* src = edge;       // edge_index[0]
  const int* dstp = edge + E;  // edge_index[1]
  float* out = (float*)d_out;

  size_t off = 0;
  auto take = [&](size_t bytes) -> void* {
    void* r = (char*)d_ws + off;
    off += (bytes + 255) & ~(size_t)255;
    return r;
  };
  int* counter = (int*)take(4);
  int* cnt = (int*)take((size_t)N * 4);
  float* dinv = (float*)take((size_t)N * 4);
  int* row_start = (int*)take((size_t)N * 4);
  int* cursor = (int*)take((size_t)N * 4);
  int2* csr = (int2*)take((size_t)E * 8);
  __half* t1 = (__half*)take((size_t)N * 128 * 2);  // gemm1 out
  __half* t2 = (__half*)take((size_t)N * 64 * 2);   // aggmm2 out
  __half* t3 = (__half*)take((size_t)N * 16 * 2);   // aggmm3 out

  // zero counter + cnt (first two regions, contiguous)
  hipMemsetAsync(d_ws, 0, 256 + (size_t)N * 4, stream);

  const int TB = 256;
  int eg = (E + TB - 1) / TB;
  int ng = (N + TB - 1) / TB;
  int nwaves = (N + 15) / 16;   // 3125
  int gblk = (nwaves + 3) / 4;  // 782
  int fblk = (N + 63) / 64;     // 782

  // gemm1 is CSR-independent; CSR build follows it in the queue.
  gemm_mfma<128, 128, float><<<gblk, 256, 0, stream>>>(x, W1, t1, N, nwaves);
  count_kernel<<<eg, TB, 0, stream>>>(dstp, cnt, E);
  alloc_kernel<<<ng, TB, 0, stream>>>(cnt, row_start, cursor, counter, dinv, N);
  scatter_kernel<<<eg, TB, 0, stream>>>(src, dstp, dinv, cursor, csr, E);

  // t2 = relu(Agg(t1)+b1) @ W2    (K=128: CPL=2, EU=4 -> 8 loads in flight)
  aggmm<128, 64, 2, 4><<<fblk, 512, 0, stream>>>(t1, W2, b1, row_start, cnt, csr, dinv, t2,
                                                 N);
  // t3 = relu(Agg(t2)+b2) @ W3    (K=64: CPL=1, EU=4)
  aggmm<64, 16, 1, 4><<<fblk, 512, 0, stream>>>(t2, W3, b2, row_start, cnt, csr, dinv, t3, N);
  // out = Agg(t3) + b3
  agg_final<<<fblk, 256, 0, stream>>>(t3, row_start, cnt, csr, dinv, b3, out, N);
}